// Round 10
// baseline (147.351 us; speedup 1.0000x reference)
//
#include <hip/hip_runtime.h>

#define HID 16
#define TLEN 1024

typedef float v4f __attribute__((ext_vector_type(4)));
typedef _Float16 half_t;
typedef _Float16 v2h __attribute__((ext_vector_type(2)));

__device__ __forceinline__ float fast_exp2(float a) { return __builtin_amdgcn_exp2f(a); }
__device__ __forceinline__ float fast_rcp(float a)  { return __builtin_amdgcn_rcpf(a); }

// tanh(a) = 1 - 2/(exp2(2a*log2e)+1)  (epilogue only, unscaled input)
__device__ __forceinline__ float fast_tanh(float a) {
    return __builtin_fmaf(-2.0f, fast_rcp(1.0f + fast_exp2(a * 2.8853900817779268f)), 1.0f);
}

// DPP row_ror within 16-lane rows, HW-verified (R4/R6/R7): dst[i] = src[(i-R)&15].
template<int R>
__device__ __forceinline__ float ror16f(float v) {
    return __builtin_bit_cast(float,
        __builtin_amdgcn_update_dpp(0, __builtin_bit_cast(int, v),
                                    0x120 + R, 0xF, 0xF, true));
}

// v_cvt_pkrtz_f16_f32 fused cvt+pack; bit_cast the __fp16 vector result.
__device__ __forceinline__ int pack_f16_rtz(float a, float b) {
    return __builtin_bit_cast(int, __builtin_amdgcn_cvt_pkrtz(a, b));
}

// f16 packed dot with f32 accumulate: d = a.x*b.x + a.y*b.y + c  (v_dot2_f32_f16)
__device__ __forceinline__ float dot2(v2h a, v2h b, float c) {
#if __has_builtin(__builtin_amdgcn_fdot2)
    return __builtin_amdgcn_fdot2(a, b, c, false);
#else
    return __builtin_fmaf((float)a.y, (float)b.y,
           __builtin_fmaf((float)a.x, (float)b.x, c));
#endif
}

// One lane per (sequence, hidden unit j). 64-thread blocks = 1 wave = 4 sequences.
// grid = B/4 = 1024 waves -> 1 wave per SIMD across 256 CUs (occupancy is
// structurally capped at 1 wave/SIMD; all gains come from the serial h->h
// chain). R10: pair-rotations moved from VALU-DPP to the DS crossbar
// (ds_bpermute) to test the "DPP ~8cy busy" hypothesis from the R9 post-mortem.
__global__ __launch_bounds__(64, 1) void gru_fused_kernel(
    const float* __restrict__ x,     // [B, T, 1]
    const float* __restrict__ W_ih,  // [48, 1]
    const float* __restrict__ W_hh,  // [48, 16]
    const float* __restrict__ b_ih,  // [48]
    const float* __restrict__ b_hh,  // [48]
    const float* __restrict__ W_fc,  // [5, 16]
    const float* __restrict__ b_fc,  // [5]
    float* __restrict__ out)         // [B, 5]
{
    const int lane = threadIdx.x;      // 0..63
    const int j    = lane & 15;        // hidden unit
    const int g    = lane >> 4;        // sequence-within-wave (0..3)
    const int b    = blockIdx.x * 4 + g;

    const float NEG_LOG2E = -1.4426950408889634f;  // sigmoid: rcp(1+exp2(-a*log2e))
    const float TWO_LOG2E =  2.8853900817779268f;  // tanh:    1-2*rcp(1+exp2(2a*log2e))

    // Per-lane weight pairs (half2) for the ror-form matvec:
    //   pair p covers k0=(j-2p)&15, k1=(j-2p-1)&15, matching rotation-by-2p of
    //   hp0 = {h_j, h_{j-1}}. Quantize AFTER scaling; h recurrence stays f32.
    v2h wrp[8], wzp[8], wnp[8];
    #pragma unroll
    for (int p = 0; p < 8; ++p) {
        const int k0 = (j - 2 * p)     & 15;
        const int k1 = (j - 2 * p - 1) & 15;
        wrp[p] = v2h{ (half_t)(W_hh[(j     ) * HID + k0] * NEG_LOG2E),
                      (half_t)(W_hh[(j     ) * HID + k1] * NEG_LOG2E) };
        wzp[p] = v2h{ (half_t)(W_hh[(j + 16) * HID + k0] * NEG_LOG2E),
                      (half_t)(W_hh[(j + 16) * HID + k1] * NEG_LOG2E) };
        wnp[p] = v2h{ (half_t)(W_hh[(j + 32) * HID + k0] * TWO_LOG2E),
                      (half_t)(W_hh[(j + 32) * HID + k1] * TWO_LOG2E) };
    }
    const float wih_r = W_ih[j]      * NEG_LOG2E;
    const float wih_z = W_ih[j + 16] * NEG_LOG2E;
    const float wih_n = W_ih[j + 32] * TWO_LOG2E;
    const float br  = (b_ih[j]      + b_hh[j])      * NEG_LOG2E;
    const float bz  = (b_ih[j + 16] + b_hh[j + 16]) * NEG_LOG2E;
    const float bnx = b_ih[j + 32] * TWO_LOG2E;    // input-side n bias
    const float bnh = b_hh[j + 32] * TWO_LOG2E;    // hidden-side n bias (inside r*)

    // ds_bpermute byte-addresses for rotation-by-2p within this 16-lane group:
    // dst[lane] = src[addr/4], addr = 4*(16g + ((j-2p)&15)). Constant VGPRs.
    const int gb4 = g * 64;   // 16g * 4 bytes
    const int bp1 = gb4 + (((j -  2) & 15) << 2);
    const int bp2 = gb4 + (((j -  4) & 15) << 2);
    const int bp3 = gb4 + (((j -  6) & 15) << 2);
    const int bp4 = gb4 + (((j -  8) & 15) << 2);
    const int bp5 = gb4 + (((j - 10) & 15) << 2);
    const int bp6 = gb4 + (((j - 12) & 15) << 2);
    const int bp7 = gb4 + (((j - 14) & 15) << 2);

    const float* __restrict__ xb = x + (size_t)b * TLEN;

    float h    = 0.0f;
    float hm1f = -1.0f;   // h - 1, maintained off the critical path
    // current chunk's 16 x values, full copy per lane (same cachelines per group)
    v4f xc0 = *(const v4f*)(xb +  0);
    v4f xc1 = *(const v4f*)(xb +  4);
    v4f xc2 = *(const v4f*)(xb +  8);
    v4f xc3 = *(const v4f*)(xb + 12);

    for (int t0 = 0; t0 < TLEN; t0 += 16) {
        // prefetch next chunk (independent of the recurrence)
        v4f xn0 = {0,0,0,0}, xn1 = {0,0,0,0}, xn2 = {0,0,0,0}, xn3 = {0,0,0,0};
        if (t0 + 16 < TLEN) {
            xn0 = *(const v4f*)(xb + t0 + 16);
            xn1 = *(const v4f*)(xb + t0 + 20);
            xn2 = *(const v4f*)(xb + t0 + 24);
            xn3 = *(const v4f*)(xb + t0 + 28);
        }

        const v4f xcs[4] = { xc0, xc1, xc2, xc3 };
        #pragma unroll
        for (int i = 0; i < 16; ++i) {
            const float xt = xcs[i >> 2][i & 3];   // compile-time indices

            // input-gate terms (independent of h -> fill latency bubbles)
            const float rx = __builtin_fmaf(xt, wih_r, br);
            const float zx = __builtin_fmaf(xt, wih_z, bz);
            const float nx = __builtin_fmaf(xt, wih_n, bnx);

            // ---- build the 8 rotated f16 h-pairs:
            //      1 DPP + 1 fused cvt+pack + 7 ds_bpermute (DS crossbar,
            //      1 issue slot each; latency hides under the h2_0..h2_2 dots) ----
            const float hm1 = ror16f<1>(h);                 // h_{j-1}
            const int hp0 = pack_f16_rtz(h, hm1);           // {h_j, h_{j-1}}
            const int hp1 = __builtin_amdgcn_ds_bpermute(bp1, hp0);
            const int hp2 = __builtin_amdgcn_ds_bpermute(bp2, hp0);
            const int hp3 = __builtin_amdgcn_ds_bpermute(bp3, hp0);
            const int hp4 = __builtin_amdgcn_ds_bpermute(bp4, hp0);
            const int hp5 = __builtin_amdgcn_ds_bpermute(bp5, hp0);
            const int hp6 = __builtin_amdgcn_ds_bpermute(bp6, hp0);
            const int hp7 = __builtin_amdgcn_ds_bpermute(bp7, hp0);
            const v2h h2_0 = __builtin_bit_cast(v2h, hp0);
            const v2h h2_1 = __builtin_bit_cast(v2h, hp1);
            const v2h h2_2 = __builtin_bit_cast(v2h, hp2);
            const v2h h2_3 = __builtin_bit_cast(v2h, hp3);
            const v2h h2_4 = __builtin_bit_cast(v2h, hp4);
            const v2h h2_5 = __builtin_bit_cast(v2h, hp5);
            const v2h h2_6 = __builtin_bit_cast(v2h, hp6);
            const v2h h2_7 = __builtin_bit_cast(v2h, hp7);

            // ---- 25 MAC ops: ar as 2 chains of 4 (+1 add) so exp2(ar) starts
            //      ~16 cy earlier; az/an single chains ----
            float ar  = dot2(wrp[0], h2_0, rx);
            float az  = dot2(wzp[0], h2_0, zx);
            float an  = dot2(wnp[0], h2_0, bnh);
            float ar2 = dot2(wrp[4], h2_4, 0.0f);
            ar  = dot2(wrp[1], h2_1, ar);
            az  = dot2(wzp[1], h2_1, az);
            an  = dot2(wnp[1], h2_1, an);
            ar2 = dot2(wrp[5], h2_5, ar2);
            ar  = dot2(wrp[2], h2_2, ar);
            az  = dot2(wzp[2], h2_2, az);
            an  = dot2(wnp[2], h2_2, an);
            ar2 = dot2(wrp[6], h2_6, ar2);
            ar  = dot2(wrp[3], h2_3, ar);
            az  = dot2(wzp[3], h2_3, az);
            an  = dot2(wnp[3], h2_3, an);
            ar2 = dot2(wrp[7], h2_7, ar2);
            ar  = ar + ar2;
            az  = dot2(wzp[4], h2_4, az);
            an  = dot2(wnp[4], h2_4, an);
            az  = dot2(wzp[5], h2_5, az);
            an  = dot2(wnp[5], h2_5, an);
            az  = dot2(wzp[6], h2_6, az);
            an  = dot2(wnp[6], h2_6, an);
            az  = dot2(wzp[7], h2_7, az);
            an  = dot2(wnp[7], h2_7, an);

            // ---- activations (weights pre-scaled: no mul before exp2) ----
            const float r_ = fast_rcp(1.0f + fast_exp2(ar));
            const float z_ = fast_rcp(1.0f + fast_exp2(az));
            const float s_ = __builtin_fmaf(r_, an, nx);
            const float v_ = fast_rcp(1.0f + fast_exp2(s_));
            // n = 1 - 2v ; h' = n + z*(h - n)
            const float n_  = __builtin_fmaf(-2.0f, v_, 1.0f);
            const float hmn = __builtin_fmaf( 2.0f, v_, hm1f);   // h - n
            h    = __builtin_fmaf(z_, hmn, n_);
            hm1f = h - 1.0f;   // off-path, feeds next step
        }

        xc0 = xn0; xc1 = xn1; xc2 = xn2; xc3 = xn3;
    }

    // --- epilogue: out[b, c] = sum_j tanh(h_j) * W_fc[c, j] + b_fc[c] ---
    __shared__ float th_s[64];
    th_s[lane] = fast_tanh(h);
    __syncthreads();

    if (j < 5) {
        float acc = b_fc[j];
        #pragma unroll
        for (int k = 0; k < HID; ++k)
            acc = __builtin_fmaf(W_fc[j * HID + k], th_s[g * HID + k], acc);
        out[(size_t)b * 5 + j] = acc;
    }
}

extern "C" void kernel_launch(void* const* d_in, const int* in_sizes, int n_in,
                              void* d_out, int out_size, void* d_ws, size_t ws_size,
                              hipStream_t stream) {
    const float* x    = (const float*)d_in[0];
    const float* W_ih = (const float*)d_in[1];
    const float* W_hh = (const float*)d_in[2];
    const float* b_ih = (const float*)d_in[3];
    const float* b_hh = (const float*)d_in[4];
    const float* W_fc = (const float*)d_in[5];
    const float* b_fc = (const float*)d_in[6];
    float* out = (float*)d_out;

    const int B = in_sizes[0] / TLEN;  // 4096
    gru_fused_kernel<<<dim3(B / 4), dim3(64), 0, stream>>>(
        x, W_ih, W_hh, b_ih, b_hh, W_fc, b_fc, out);
}

// Round 11
// 128.474 us; speedup vs baseline: 1.1469x; 1.1469x over previous
//
#include <hip/hip_runtime.h>

#define HID 16
#define TLEN 1024

typedef float v4f __attribute__((ext_vector_type(4)));
typedef _Float16 half_t;
typedef _Float16 v2h __attribute__((ext_vector_type(2)));

__device__ __forceinline__ float fast_exp2(float a) { return __builtin_amdgcn_exp2f(a); }
__device__ __forceinline__ float fast_rcp(float a)  { return __builtin_amdgcn_rcpf(a); }

// tanh(a) = 1 - 2/(exp2(2a*log2e)+1)  (epilogue only, unscaled input)
__device__ __forceinline__ float fast_tanh(float a) {
    return __builtin_fmaf(-2.0f, fast_rcp(1.0f + fast_exp2(a * 2.8853900817779268f)), 1.0f);
}

// DPP row_ror within 16-lane rows, HW-verified (R4/R6/R7): dst[i] = src[(i-R)&15].
template<int R>
__device__ __forceinline__ float ror16f(float v) {
    return __builtin_bit_cast(float,
        __builtin_amdgcn_update_dpp(0, __builtin_bit_cast(int, v),
                                    0x120 + R, 0xF, 0xF, true));
}
template<int R>
__device__ __forceinline__ int ror16i(int v) {
    return __builtin_amdgcn_update_dpp(0, v, 0x120 + R, 0xF, 0xF, true);
}

// v_cvt_pkrtz_f16_f32 fused cvt+pack; bit_cast the __fp16 vector result.
__device__ __forceinline__ int pack_f16_rtz(float a, float b) {
    return __builtin_bit_cast(int, __builtin_amdgcn_cvt_pkrtz(a, b));
}

// f16 packed dot with f32 accumulate: d = a.x*b.x + a.y*b.y + c  (v_dot2_f32_f16)
__device__ __forceinline__ float dot2(v2h a, v2h b, float c) {
#if __has_builtin(__builtin_amdgcn_fdot2)
    return __builtin_amdgcn_fdot2(a, b, c, false);
#else
    return __builtin_fmaf((float)a.y, (float)b.y,
           __builtin_fmaf((float)a.x, (float)b.x, c));
#endif
}

#define SCHED_FENCE() __builtin_amdgcn_sched_barrier(0)

// One lane per (sequence, hidden unit j). 64-thread blocks = 1 wave = 4 sequences.
// grid = B/4 = 1024 waves -> 1 wave per SIMD across 256 CUs.
// R11: issue floor reached (~198 busy cy/step); this round pipelines the
// activation (trans) chains INTO the dot stream via source order + 3
// sched_barrier seams, attacking the ~70 cy/step latency tail.
__global__ __launch_bounds__(64, 1) void gru_fused_kernel(
    const float* __restrict__ x,     // [B, T, 1]
    const float* __restrict__ W_ih,  // [48, 1]
    const float* __restrict__ W_hh,  // [48, 16]
    const float* __restrict__ b_ih,  // [48]
    const float* __restrict__ b_hh,  // [48]
    const float* __restrict__ W_fc,  // [5, 16]
    const float* __restrict__ b_fc,  // [5]
    float* __restrict__ out)         // [B, 5]
{
    const int lane = threadIdx.x;      // 0..63
    const int j    = lane & 15;        // hidden unit
    const int g    = lane >> 4;        // sequence-within-wave (0..3)
    const int b    = blockIdx.x * 4 + g;

    const float NEG_LOG2E = -1.4426950408889634f;  // sigmoid: rcp(1+exp2(-a*log2e))
    const float TWO_LOG2E =  2.8853900817779268f;  // tanh:    1-2*rcp(1+exp2(2a*log2e))

    // Per-lane weight pairs (half2): pair p covers k0=(j-2p)&15, k1=(j-2p-1)&15,
    // matching rotation-by-2p of hp0 = {h_j, h_{j-1}}. Pre-scaled for exp2.
    v2h wrp[8], wzp[8], wnp[8];
    #pragma unroll
    for (int p = 0; p < 8; ++p) {
        const int k0 = (j - 2 * p)     & 15;
        const int k1 = (j - 2 * p - 1) & 15;
        wrp[p] = v2h{ (half_t)(W_hh[(j     ) * HID + k0] * NEG_LOG2E),
                      (half_t)(W_hh[(j     ) * HID + k1] * NEG_LOG2E) };
        wzp[p] = v2h{ (half_t)(W_hh[(j + 16) * HID + k0] * NEG_LOG2E),
                      (half_t)(W_hh[(j + 16) * HID + k1] * NEG_LOG2E) };
        wnp[p] = v2h{ (half_t)(W_hh[(j + 32) * HID + k0] * TWO_LOG2E),
                      (half_t)(W_hh[(j + 32) * HID + k1] * TWO_LOG2E) };
    }
    const float wih_r = W_ih[j]      * NEG_LOG2E;
    const float wih_z = W_ih[j + 16] * NEG_LOG2E;
    const float wih_n = W_ih[j + 32] * TWO_LOG2E;
    const float br  = (b_ih[j]      + b_hh[j])      * NEG_LOG2E;
    const float bz  = (b_ih[j + 16] + b_hh[j + 16]) * NEG_LOG2E;
    const float bnx = b_ih[j + 32] * TWO_LOG2E;    // input-side n bias
    const float bnh = b_hh[j + 32] * TWO_LOG2E;    // hidden-side n bias (inside r*)

    const float* __restrict__ xb = x + (size_t)b * TLEN;

    float h    = 0.0f;
    float hm1f = -1.0f;   // h - 1, maintained off the critical path
    v4f xc0 = *(const v4f*)(xb +  0);
    v4f xc1 = *(const v4f*)(xb +  4);
    v4f xc2 = *(const v4f*)(xb +  8);
    v4f xc3 = *(const v4f*)(xb + 12);

    for (int t0 = 0; t0 < TLEN; t0 += 16) {
        // prefetch next chunk (independent of the recurrence)
        v4f xn0 = {0,0,0,0}, xn1 = {0,0,0,0}, xn2 = {0,0,0,0}, xn3 = {0,0,0,0};
        if (t0 + 16 < TLEN) {
            xn0 = *(const v4f*)(xb + t0 + 16);
            xn1 = *(const v4f*)(xb + t0 + 20);
            xn2 = *(const v4f*)(xb + t0 + 24);
            xn3 = *(const v4f*)(xb + t0 + 28);
        }

        const v4f xcs[4] = { xc0, xc1, xc2, xc3 };
        #pragma unroll
        for (int i = 0; i < 16; ++i) {
            const float xt = xcs[i >> 2][i & 3];   // compile-time indices

            // ============ PHASE 1: inputs, rotations, r-gate dots ============
            const float rx = __builtin_fmaf(xt, wih_r, br);
            const float zx = __builtin_fmaf(xt, wih_z, bz);
            const float nx = __builtin_fmaf(xt, wih_n, bnx);

            const float hm1 = ror16f<1>(h);                 // h_{j-1}
            const int hp0 = pack_f16_rtz(h, hm1);           // {h_j, h_{j-1}}
            const int hp1 = ror16i< 2>(hp0);
            const int hp2 = ror16i< 4>(hp0);
            const int hp3 = ror16i< 6>(hp0);
            const int hp4 = ror16i< 8>(hp0);
            const int hp5 = ror16i<10>(hp0);
            const int hp6 = ror16i<12>(hp0);
            const int hp7 = ror16i<14>(hp0);
            const v2h h2_0 = __builtin_bit_cast(v2h, hp0);
            const v2h h2_1 = __builtin_bit_cast(v2h, hp1);
            const v2h h2_2 = __builtin_bit_cast(v2h, hp2);
            const v2h h2_3 = __builtin_bit_cast(v2h, hp3);
            const v2h h2_4 = __builtin_bit_cast(v2h, hp4);
            const v2h h2_5 = __builtin_bit_cast(v2h, hp5);
            const v2h h2_6 = __builtin_bit_cast(v2h, hp6);
            const v2h h2_7 = __builtin_bit_cast(v2h, hp7);

            // ar: 2 chains of 4 -> completes earliest
            float ar  = dot2(wrp[0], h2_0, rx);
            float ar2 = dot2(wrp[4], h2_4, 0.0f);
            ar  = dot2(wrp[1], h2_1, ar);
            ar2 = dot2(wrp[5], h2_5, ar2);
            ar  = dot2(wrp[2], h2_2, ar);
            ar2 = dot2(wrp[6], h2_6, ar2);
            ar  = dot2(wrp[3], h2_3, ar);
            ar2 = dot2(wrp[7], h2_7, ar2);
            ar  = ar + ar2;
            // start n-gate dots (fill ar tail latency)
            float anA = dot2(wnp[0], h2_0, bnh);
            float anB = dot2(wnp[4], h2_4, 0.0f);
            SCHED_FENCE();

            // ============ PHASE 2: r-sigmoid buried under n/z dots ============
            const float eA = fast_exp2(ar);
            anA = dot2(wnp[1], h2_1, anA);
            anB = dot2(wnp[5], h2_5, anB);
            anA = dot2(wnp[2], h2_2, anA);
            const float dA = 1.0f + eA;
            anB = dot2(wnp[6], h2_6, anB);
            const float rA = fast_rcp(dA);
            anA = dot2(wnp[3], h2_3, anA);
            anB = dot2(wnp[7], h2_7, anB);
            float az = dot2(wzp[0], h2_0, zx);
            az = dot2(wzp[1], h2_1, az);
            const float an = anA + anB;
            az = dot2(wzp[2], h2_2, az);
            az = dot2(wzp[3], h2_3, az);
            SCHED_FENCE();

            // ============ PHASE 3: tanh chain, z-sigmoid overlapped ============
            const float s_ = __builtin_fmaf(rA, an, nx);
            az = dot2(wzp[4], h2_4, az);
            az = dot2(wzp[5], h2_5, az);
            const float eS = fast_exp2(s_);
            az = dot2(wzp[6], h2_6, az);
            az = dot2(wzp[7], h2_7, az);
            const float eZ = fast_exp2(az);       // pipelines behind eS on trans unit
            const float dS = 1.0f + eS;
            const float dZ = 1.0f + eZ;
            const float vS = fast_rcp(dS);
            const float rZ = fast_rcp(dZ);
            // n = 1 - 2v ; h' = n + z*(h - n)
            const float n_  = __builtin_fmaf(-2.0f, vS, 1.0f);
            const float hmn = __builtin_fmaf( 2.0f, vS, hm1f);   // h - n
            h    = __builtin_fmaf(rZ, hmn, n_);
            hm1f = h - 1.0f;   // off-path, feeds next step
            SCHED_FENCE();
        }

        xc0 = xn0; xc1 = xn1; xc2 = xn2; xc3 = xn3;
    }

    // --- epilogue: out[b, c] = sum_j tanh(h_j) * W_fc[c, j] + b_fc[c] ---
    __shared__ float th_s[64];
    th_s[lane] = fast_tanh(h);
    __syncthreads();

    if (j < 5) {
        float acc = b_fc[j];
        #pragma unroll
        for (int k = 0; k < HID; ++k)
            acc = __builtin_fmaf(W_fc[j * HID + k], th_s[g * HID + k], acc);
        out[(size_t)b * 5 + j] = acc;
    }
}

extern "C" void kernel_launch(void* const* d_in, const int* in_sizes, int n_in,
                              void* d_out, int out_size, void* d_ws, size_t ws_size,
                              hipStream_t stream) {
    const float* x    = (const float*)d_in[0];
    const float* W_ih = (const float*)d_in[1];
    const float* W_hh = (const float*)d_in[2];
    const float* b_ih = (const float*)d_in[3];
    const float* b_hh = (const float*)d_in[4];
    const float* W_fc = (const float*)d_in[5];
    const float* b_fc = (const float*)d_in[6];
    float* out = (float*)d_out;

    const int B = in_sizes[0] / TLEN;  // 4096
    gru_fused_kernel<<<dim3(B / 4), dim3(64), 0, stream>>>(
        x, W_ih, W_hh, b_ih, b_hh, W_fc, b_fc, out);
}

// Round 12
// 123.274 us; speedup vs baseline: 1.1953x; 1.0422x over previous
//
#include <hip/hip_runtime.h>

#define HID 16
#define TLEN 1024

typedef float v4f __attribute__((ext_vector_type(4)));
typedef _Float16 half_t;
typedef _Float16 v2h __attribute__((ext_vector_type(2)));

__device__ __forceinline__ float fast_exp2(float a) { return __builtin_amdgcn_exp2f(a); }
__device__ __forceinline__ float fast_rcp(float a)  { return __builtin_amdgcn_rcpf(a); }

// tanh(a) = 1 - 2/(exp2(2a*log2e)+1)  (epilogue only, unscaled input)
__device__ __forceinline__ float fast_tanh(float a) {
    return __builtin_fmaf(-2.0f, fast_rcp(1.0f + fast_exp2(a * 2.8853900817779268f)), 1.0f);
}

// DPP row_ror within 16-lane rows, HW-verified (R4/R6/R7): dst[i] = src[(i-R)&15].
template<int R>
__device__ __forceinline__ float ror16f(float v) {
    return __builtin_bit_cast(float,
        __builtin_amdgcn_update_dpp(0, __builtin_bit_cast(int, v),
                                    0x120 + R, 0xF, 0xF, true));
}
template<int R>
__device__ __forceinline__ int ror16i(int v) {
    return __builtin_amdgcn_update_dpp(0, v, 0x120 + R, 0xF, 0xF, true);
}

// v_cvt_pkrtz_f16_f32 fused cvt+pack; bit_cast the __fp16 vector result.
__device__ __forceinline__ int pack_f16_rtz(float a, float b) {
    return __builtin_bit_cast(int, __builtin_amdgcn_cvt_pkrtz(a, b));
}

// f16 packed dot with f32 accumulate: d = a.x*b.x + a.y*b.y + c  (v_dot2_f32_f16)
__device__ __forceinline__ float dot2(v2h a, v2h b, float c) {
#if __has_builtin(__builtin_amdgcn_fdot2)
    return __builtin_amdgcn_fdot2(a, b, c, false);
#else
    return __builtin_fmaf((float)a.y, (float)b.y,
           __builtin_fmaf((float)a.x, (float)b.x, c));
#endif
}

// One lane per (sequence, hidden unit j). 64-thread blocks = 1 wave = 4 sequences.
// grid = B/4 = 1024 waves -> 1 wave per SIMD across 256 CUs.
// R12: R11's dependency graph (split ar chain -> earliest r-sigmoid; az last)
// with the sched_barrier fences REMOVED — isolates "fences hurt" from
// "reorder hurt". Compiler schedules freely over the whole step body.
__global__ __launch_bounds__(64, 1) void gru_fused_kernel(
    const float* __restrict__ x,     // [B, T, 1]
    const float* __restrict__ W_ih,  // [48, 1]
    const float* __restrict__ W_hh,  // [48, 16]
    const float* __restrict__ b_ih,  // [48]
    const float* __restrict__ b_hh,  // [48]
    const float* __restrict__ W_fc,  // [5, 16]
    const float* __restrict__ b_fc,  // [5]
    float* __restrict__ out)         // [B, 5]
{
    const int lane = threadIdx.x;      // 0..63
    const int j    = lane & 15;        // hidden unit
    const int g    = lane >> 4;        // sequence-within-wave (0..3)
    const int b    = blockIdx.x * 4 + g;

    const float NEG_LOG2E = -1.4426950408889634f;  // sigmoid: rcp(1+exp2(-a*log2e))
    const float TWO_LOG2E =  2.8853900817779268f;  // tanh:    1-2*rcp(1+exp2(2a*log2e))

    // Per-lane weight pairs (half2): pair p covers k0=(j-2p)&15, k1=(j-2p-1)&15,
    // matching rotation-by-2p of hp0 = {h_j, h_{j-1}}. Pre-scaled for exp2.
    v2h wrp[8], wzp[8], wnp[8];
    #pragma unroll
    for (int p = 0; p < 8; ++p) {
        const int k0 = (j - 2 * p)     & 15;
        const int k1 = (j - 2 * p - 1) & 15;
        wrp[p] = v2h{ (half_t)(W_hh[(j     ) * HID + k0] * NEG_LOG2E),
                      (half_t)(W_hh[(j     ) * HID + k1] * NEG_LOG2E) };
        wzp[p] = v2h{ (half_t)(W_hh[(j + 16) * HID + k0] * NEG_LOG2E),
                      (half_t)(W_hh[(j + 16) * HID + k1] * NEG_LOG2E) };
        wnp[p] = v2h{ (half_t)(W_hh[(j + 32) * HID + k0] * TWO_LOG2E),
                      (half_t)(W_hh[(j + 32) * HID + k1] * TWO_LOG2E) };
    }
    const float wih_r = W_ih[j]      * NEG_LOG2E;
    const float wih_z = W_ih[j + 16] * NEG_LOG2E;
    const float wih_n = W_ih[j + 32] * TWO_LOG2E;
    const float br  = (b_ih[j]      + b_hh[j])      * NEG_LOG2E;
    const float bz  = (b_ih[j + 16] + b_hh[j + 16]) * NEG_LOG2E;
    const float bnx = b_ih[j + 32] * TWO_LOG2E;    // input-side n bias
    const float bnh = b_hh[j + 32] * TWO_LOG2E;    // hidden-side n bias (inside r*)

    const float* __restrict__ xb = x + (size_t)b * TLEN;

    float h    = 0.0f;
    float hm1f = -1.0f;   // h - 1, maintained off the critical path
    v4f xc0 = *(const v4f*)(xb +  0);
    v4f xc1 = *(const v4f*)(xb +  4);
    v4f xc2 = *(const v4f*)(xb +  8);
    v4f xc3 = *(const v4f*)(xb + 12);

    for (int t0 = 0; t0 < TLEN; t0 += 16) {
        // prefetch next chunk (independent of the recurrence)
        v4f xn0 = {0,0,0,0}, xn1 = {0,0,0,0}, xn2 = {0,0,0,0}, xn3 = {0,0,0,0};
        if (t0 + 16 < TLEN) {
            xn0 = *(const v4f*)(xb + t0 + 16);
            xn1 = *(const v4f*)(xb + t0 + 20);
            xn2 = *(const v4f*)(xb + t0 + 24);
            xn3 = *(const v4f*)(xb + t0 + 28);
        }

        const v4f xcs[4] = { xc0, xc1, xc2, xc3 };
        #pragma unroll
        for (int i = 0; i < 16; ++i) {
            const float xt = xcs[i >> 2][i & 3];   // compile-time indices

            // inputs and rotations
            const float rx = __builtin_fmaf(xt, wih_r, br);
            const float zx = __builtin_fmaf(xt, wih_z, bz);
            const float nx = __builtin_fmaf(xt, wih_n, bnx);

            const float hm1 = ror16f<1>(h);                 // h_{j-1}
            const int hp0 = pack_f16_rtz(h, hm1);           // {h_j, h_{j-1}}
            const int hp1 = ror16i< 2>(hp0);
            const int hp2 = ror16i< 4>(hp0);
            const int hp3 = ror16i< 6>(hp0);
            const int hp4 = ror16i< 8>(hp0);
            const int hp5 = ror16i<10>(hp0);
            const int hp6 = ror16i<12>(hp0);
            const int hp7 = ror16i<14>(hp0);
            const v2h h2_0 = __builtin_bit_cast(v2h, hp0);
            const v2h h2_1 = __builtin_bit_cast(v2h, hp1);
            const v2h h2_2 = __builtin_bit_cast(v2h, hp2);
            const v2h h2_3 = __builtin_bit_cast(v2h, hp3);
            const v2h h2_4 = __builtin_bit_cast(v2h, hp4);
            const v2h h2_5 = __builtin_bit_cast(v2h, hp5);
            const v2h h2_6 = __builtin_bit_cast(v2h, hp6);
            const v2h h2_7 = __builtin_bit_cast(v2h, hp7);

            // ar: 2 chains of 4 -> r-sigmoid input ready earliest
            float ar  = dot2(wrp[0], h2_0, rx);
            float ar2 = dot2(wrp[4], h2_4, 0.0f);
            ar  = dot2(wrp[1], h2_1, ar);
            ar2 = dot2(wrp[5], h2_5, ar2);
            ar  = dot2(wrp[2], h2_2, ar);
            ar2 = dot2(wrp[6], h2_6, ar2);
            ar  = dot2(wrp[3], h2_3, ar);
            ar2 = dot2(wrp[7], h2_7, ar2);
            ar  = ar + ar2;

            // r-sigmoid (latency hidden under n/z dots below by the scheduler)
            const float eA = fast_exp2(ar);
            float anA = dot2(wnp[0], h2_0, bnh);
            float anB = dot2(wnp[4], h2_4, 0.0f);
            anA = dot2(wnp[1], h2_1, anA);
            anB = dot2(wnp[5], h2_5, anB);
            const float dA = 1.0f + eA;
            anA = dot2(wnp[2], h2_2, anA);
            anB = dot2(wnp[6], h2_6, anB);
            const float rA = fast_rcp(dA);
            anA = dot2(wnp[3], h2_3, anA);
            anB = dot2(wnp[7], h2_7, anB);
            const float an = anA + anB;

            float az = dot2(wzp[0], h2_0, zx);
            az = dot2(wzp[1], h2_1, az);
            az = dot2(wzp[2], h2_2, az);
            az = dot2(wzp[3], h2_3, az);

            // tanh chain; z-dots and z-sigmoid overlap it
            const float s_ = __builtin_fmaf(rA, an, nx);
            az = dot2(wzp[4], h2_4, az);
            az = dot2(wzp[5], h2_5, az);
            const float eS = fast_exp2(s_);
            az = dot2(wzp[6], h2_6, az);
            az = dot2(wzp[7], h2_7, az);
            const float eZ = fast_exp2(az);
            const float dS = 1.0f + eS;
            const float dZ = 1.0f + eZ;
            const float vS = fast_rcp(dS);
            const float rZ = fast_rcp(dZ);
            // n = 1 - 2v ; h' = n + z*(h - n)
            const float n_  = __builtin_fmaf(-2.0f, vS, 1.0f);
            const float hmn = __builtin_fmaf( 2.0f, vS, hm1f);   // h - n
            h    = __builtin_fmaf(rZ, hmn, n_);
            hm1f = h - 1.0f;   // off-path, feeds next step
        }

        xc0 = xn0; xc1 = xn1; xc2 = xn2; xc3 = xn3;
    }

    // --- epilogue: out[b, c] = sum_j tanh(h_j) * W_fc[c, j] + b_fc[c] ---
    __shared__ float th_s[64];
    th_s[lane] = fast_tanh(h);
    __syncthreads();

    if (j < 5) {
        float acc = b_fc[j];
        #pragma unroll
        for (int k = 0; k < HID; ++k)
            acc = __builtin_fmaf(W_fc[j * HID + k], th_s[g * HID + k], acc);
        out[(size_t)b * 5 + j] = acc;
    }
}

extern "C" void kernel_launch(void* const* d_in, const int* in_sizes, int n_in,
                              void* d_out, int out_size, void* d_ws, size_t ws_size,
                              hipStream_t stream) {
    const float* x    = (const float*)d_in[0];
    const float* W_ih = (const float*)d_in[1];
    const float* W_hh = (const float*)d_in[2];
    const float* b_ih = (const float*)d_in[3];
    const float* b_hh = (const float*)d_in[4];
    const float* W_fc = (const float*)d_in[5];
    const float* b_fc = (const float*)d_in[6];
    float* out = (float*)d_out;

    const int B = in_sizes[0] / TLEN;  // 4096
    gru_fused_kernel<<<dim3(B / 4), dim3(64), 0, stream>>>(
        x, W_ih, W_hh, b_ih, b_hh, W_fc, b_fc, out);
}

// Round 13
// 114.584 us; speedup vs baseline: 1.2860x; 1.0758x over previous
//
#include <hip/hip_runtime.h>

#define HID 16
#define TLEN 1024

typedef float v4f __attribute__((ext_vector_type(4)));
typedef _Float16 half_t;
typedef _Float16 v2h __attribute__((ext_vector_type(2)));

__device__ __forceinline__ float fast_exp2(float a) { return __builtin_amdgcn_exp2f(a); }
__device__ __forceinline__ float fast_rcp(float a)  { return __builtin_amdgcn_rcpf(a); }

// tanh(a) = 1 - 2/(exp2(2a*log2e)+1)  (epilogue only, unscaled input)
__device__ __forceinline__ float fast_tanh(float a) {
    return __builtin_fmaf(-2.0f, fast_rcp(1.0f + fast_exp2(a * 2.8853900817779268f)), 1.0f);
}

// DPP row_ror within 16-lane rows, HW-verified (R4/R6/R7): dst[i] = src[(i-R)&15].
template<int R>
__device__ __forceinline__ float ror16f(float v) {
    return __builtin_bit_cast(float,
        __builtin_amdgcn_update_dpp(0, __builtin_bit_cast(int, v),
                                    0x120 + R, 0xF, 0xF, true));
}
template<int R>
__device__ __forceinline__ int ror16i(int v) {
    return __builtin_amdgcn_update_dpp(0, v, 0x120 + R, 0xF, 0xF, true);
}

// f16 packed dot with f32 accumulate: d = a.x*b.x + a.y*b.y + c  (v_dot2_f32_f16)
__device__ __forceinline__ float dot2(v2h a, v2h b, float c) {
#if __has_builtin(__builtin_amdgcn_fdot2)
    return __builtin_amdgcn_fdot2(a, b, c, false);
#else
    return __builtin_fmaf((float)a.y, (float)b.y,
           __builtin_fmaf((float)a.x, (float)b.x, c));
#endif
}

// One lane per (sequence, hidden unit j). 64-thread blocks = 1 wave = 4 sequences.
// grid = B/4 = 1024 waves -> 1 wave per SIMD across 256 CUs (occupancy is
// structurally capped at 1 wave/SIMD; all gains come from the serial h->h
// chain). R13: exact revert to the best-measured variant (R7, 114.6 us) —
// compiler-scheduled plain source; hand-reordering (R11/R12), fences (R11),
// DS rotations (R10), and micro-trims (R9) all measured neutral-to-worse.
__global__ __launch_bounds__(64, 1) void gru_fused_kernel(
    const float* __restrict__ x,     // [B, T, 1]
    const float* __restrict__ W_ih,  // [48, 1]
    const float* __restrict__ W_hh,  // [48, 16]
    const float* __restrict__ b_ih,  // [48]
    const float* __restrict__ b_hh,  // [48]
    const float* __restrict__ W_fc,  // [5, 16]
    const float* __restrict__ b_fc,  // [5]
    float* __restrict__ out)         // [B, 5]
{
    const int lane = threadIdx.x;      // 0..63
    const int j    = lane & 15;        // hidden unit
    const int g    = lane >> 4;        // sequence-within-wave (0..3)
    const int b    = blockIdx.x * 4 + g;

    const float NEG_LOG2E = -1.4426950408889634f;  // sigmoid: rcp(1+exp2(-a*log2e))
    const float TWO_LOG2E =  2.8853900817779268f;  // tanh:    1-2*rcp(1+exp2(2a*log2e))

    // Per-lane weight pairs (half2) for the ror-form matvec:
    //   pair p covers k0=(j-2p)&15, k1=(j-2p-1)&15, matching row_ror:2p of
    //   hp0 = {h_j, h_{j-1}}. Quantize AFTER scaling; h recurrence stays f32.
    v2h wrp[8], wzp[8], wnp[8];
    #pragma unroll
    for (int p = 0; p < 8; ++p) {
        const int k0 = (j - 2 * p)     & 15;
        const int k1 = (j - 2 * p - 1) & 15;
        wrp[p] = v2h{ (half_t)(W_hh[(j     ) * HID + k0] * NEG_LOG2E),
                      (half_t)(W_hh[(j     ) * HID + k1] * NEG_LOG2E) };
        wzp[p] = v2h{ (half_t)(W_hh[(j + 16) * HID + k0] * NEG_LOG2E),
                      (half_t)(W_hh[(j + 16) * HID + k1] * NEG_LOG2E) };
        wnp[p] = v2h{ (half_t)(W_hh[(j + 32) * HID + k0] * TWO_LOG2E),
                      (half_t)(W_hh[(j + 32) * HID + k1] * TWO_LOG2E) };
    }
    const float wih_r = W_ih[j]      * NEG_LOG2E;
    const float wih_z = W_ih[j + 16] * NEG_LOG2E;
    const float wih_n = W_ih[j + 32] * TWO_LOG2E;
    const float br  = (b_ih[j]      + b_hh[j])      * NEG_LOG2E;
    const float bz  = (b_ih[j + 16] + b_hh[j + 16]) * NEG_LOG2E;
    const float bnx = b_ih[j + 32] * TWO_LOG2E;    // input-side n bias
    const float bnh = b_hh[j + 32] * TWO_LOG2E;    // hidden-side n bias (inside r*)

    const float* __restrict__ xb = x + (size_t)b * TLEN;

    float h = 0.0f;
    // current chunk's 16 x values, full copy per lane (same cachelines per group)
    v4f xc0 = *(const v4f*)(xb +  0);
    v4f xc1 = *(const v4f*)(xb +  4);
    v4f xc2 = *(const v4f*)(xb +  8);
    v4f xc3 = *(const v4f*)(xb + 12);

    for (int t0 = 0; t0 < TLEN; t0 += 16) {
        // prefetch next chunk (independent of the recurrence)
        v4f xn0 = {0,0,0,0}, xn1 = {0,0,0,0}, xn2 = {0,0,0,0}, xn3 = {0,0,0,0};
        if (t0 + 16 < TLEN) {
            xn0 = *(const v4f*)(xb + t0 + 16);
            xn1 = *(const v4f*)(xb + t0 + 20);
            xn2 = *(const v4f*)(xb + t0 + 24);
            xn3 = *(const v4f*)(xb + t0 + 28);
        }

        const v4f xcs[4] = { xc0, xc1, xc2, xc3 };
        #pragma unroll
        for (int i = 0; i < 16; ++i) {
            const float xt = xcs[i >> 2][i & 3];   // compile-time indices

            // input-gate terms (independent of h -> fill latency bubbles)
            const float rx = __builtin_fmaf(xt, wih_r, br);
            const float zx = __builtin_fmaf(xt, wih_z, bz);
            const float nx = __builtin_fmaf(xt, wih_n, bnx);

            // ---- build the 8 rotated f16 h-pairs: 1 f32 DPP + pack + 7 packed DPPs ----
            const float hm1 = ror16f<1>(h);                 // h_{j-1}
            v2h hpv; hpv.x = (half_t)h; hpv.y = (half_t)hm1;
            const int hp0 = __builtin_bit_cast(int, hpv);   // {h_j, h_{j-1}}
            const int hp1 = ror16i< 2>(hp0);
            const int hp2 = ror16i< 4>(hp0);
            const int hp3 = ror16i< 6>(hp0);
            const int hp4 = ror16i< 8>(hp0);
            const int hp5 = ror16i<10>(hp0);
            const int hp6 = ror16i<12>(hp0);
            const int hp7 = ror16i<14>(hp0);
            const v2h h2_0 = __builtin_bit_cast(v2h, hp0);
            const v2h h2_1 = __builtin_bit_cast(v2h, hp1);
            const v2h h2_2 = __builtin_bit_cast(v2h, hp2);
            const v2h h2_3 = __builtin_bit_cast(v2h, hp3);
            const v2h h2_4 = __builtin_bit_cast(v2h, hp4);
            const v2h h2_5 = __builtin_bit_cast(v2h, hp5);
            const v2h h2_6 = __builtin_bit_cast(v2h, hp6);
            const v2h h2_7 = __builtin_bit_cast(v2h, hp7);

            // ---- 24 x v_dot2_f32_f16, 3 round-robin accumulator chains ----
            float ar = rx, az = zx, an = bnh;
            ar = dot2(wrp[0], h2_0, ar);
            az = dot2(wzp[0], h2_0, az);
            an = dot2(wnp[0], h2_0, an);
            ar = dot2(wrp[1], h2_1, ar);
            az = dot2(wzp[1], h2_1, az);
            an = dot2(wnp[1], h2_1, an);
            ar = dot2(wrp[2], h2_2, ar);
            az = dot2(wzp[2], h2_2, az);
            an = dot2(wnp[2], h2_2, an);
            ar = dot2(wrp[3], h2_3, ar);
            az = dot2(wzp[3], h2_3, az);
            an = dot2(wnp[3], h2_3, an);
            ar = dot2(wrp[4], h2_4, ar);
            az = dot2(wzp[4], h2_4, az);
            an = dot2(wnp[4], h2_4, an);
            ar = dot2(wrp[5], h2_5, ar);
            az = dot2(wzp[5], h2_5, az);
            an = dot2(wnp[5], h2_5, an);
            ar = dot2(wrp[6], h2_6, ar);
            az = dot2(wzp[6], h2_6, az);
            an = dot2(wnp[6], h2_6, an);
            ar = dot2(wrp[7], h2_7, ar);
            az = dot2(wzp[7], h2_7, az);
            an = dot2(wnp[7], h2_7, an);

            // activations (weights pre-scaled: no mul before exp2)
            const float r_ = fast_rcp(1.0f + fast_exp2(ar));
            const float z_ = fast_rcp(1.0f + fast_exp2(az));
            const float s_ = __builtin_fmaf(r_, an, nx);
            const float n_ = __builtin_fmaf(-2.0f, fast_rcp(1.0f + fast_exp2(s_)), 1.0f);

            // h = (1-z)*n + z*h
            h = __builtin_fmaf(z_, h - n_, n_);
        }

        xc0 = xn0; xc1 = xn1; xc2 = xn2; xc3 = xn3;
    }

    // --- epilogue: out[b, c] = sum_j tanh(h_j) * W_fc[c, j] + b_fc[c] ---
    __shared__ float th_s[64];
    th_s[lane] = fast_tanh(h);
    __syncthreads();

    if (j < 5) {
        float acc = b_fc[j];
        #pragma unroll
        for (int k = 0; k < HID; ++k)
            acc = __builtin_fmaf(W_fc[j * HID + k], th_s[g * HID + k], acc);
        out[(size_t)b * 5 + j] = acc;
    }
}

extern "C" void kernel_launch(void* const* d_in, const int* in_sizes, int n_in,
                              void* d_out, int out_size, void* d_ws, size_t ws_size,
                              hipStream_t stream) {
    const float* x    = (const float*)d_in[0];
    const float* W_ih = (const float*)d_in[1];
    const float* W_hh = (const float*)d_in[2];
    const float* b_ih = (const float*)d_in[3];
    const float* b_hh = (const float*)d_in[4];
    const float* W_fc = (const float*)d_in[5];
    const float* b_fc = (const float*)d_in[6];
    float* out = (float*)d_out;

    const int B = in_sizes[0] / TLEN;  // 4096
    gru_fused_kernel<<<dim3(B / 4), dim3(64), 0, stream>>>(
        x, W_ih, W_hh, b_ih, b_hh, W_fc, b_fc, out);
}